// Round 3
// baseline (695.265 us; speedup 1.0000x reference)
//
#include <hip/hip_runtime.h>

typedef unsigned long long u64;

#define NNODES 12288
#define WORDS 192   // 12288 / 64 bits per row
#define ELLW 256    // max neighbors per row (avg 64, Poisson tail safe)

// ---------------- adjacency build: bitmask M[s][d], MT[d][s] ----------------
__global__ void build_mask_kernel(const int* __restrict__ ei, u64* __restrict__ M,
                                  u64* __restrict__ MT, int E) {
    int e = blockIdx.x * blockDim.x + threadIdx.x;
    if (e >= E) return;
    int s = ei[e];
    int d = ei[E + e];
    atomicOr(&M[(size_t)s * WORDS + (d >> 6)], 1ull << (d & 63));
    atomicOr(&MT[(size_t)d * WORDS + (s >> 6)], 1ull << (s & 63));
}

// ---------------- bitmask -> ELL neighbor list + cnt + dinv ----------------
__global__ __launch_bounds__(256) void ell_fill_kernel(
        const u64* __restrict__ M, const u64* __restrict__ MT,
        int* __restrict__ ell, int* __restrict__ cnt, float* __restrict__ dinv) {
    int row = blockIdx.x * 4 + (threadIdx.x >> 6);
    int lane = threadIdx.x & 63;
    const u64* rM  = M  + (size_t)row * WORDS;
    const u64* rMT = MT + (size_t)row * WORDS;
    u64 wm[3], wt[3];
    int pm = 0, pt = 0;
    #pragma unroll
    for (int k = 0; k < 3; ++k) {
        wm[k] = rM[lane + 64 * k];  pm += __popcll(wm[k]);
        wt[k] = rMT[lane + 64 * k]; pt += __popcll(wt[k]);
    }
    int inclM = pm, inclT = pt;
    #pragma unroll
    for (int off = 1; off < 64; off <<= 1) {
        int ym = __shfl_up(inclM, off, 64);
        int yt = __shfl_up(inclT, off, 64);
        if (lane >= off) { inclM += ym; inclT += yt; }
    }
    int exclM = inclM - pm;
    int exclT = inclT - pt;
    int totM = __shfl(inclM, 63, 64);
    int totT = __shfl(inclT, 63, 64);
    int* out = ell + (size_t)row * ELLW;
    int pos = exclM;
    #pragma unroll
    for (int k = 0; k < 3; ++k) {
        u64 bits = wm[k];
        int base = (lane + 64 * k) << 6;
        while (bits) { out[pos++] = base + __builtin_ctzll(bits); bits &= bits - 1; }
    }
    pos = totM + exclT;
    #pragma unroll
    for (int k = 0; k < 3; ++k) {
        u64 bits = wt[k];
        int base = (lane + 64 * k) << 6;
        while (bits) { out[pos++] = base + __builtin_ctzll(bits); bits &= bits - 1; }
    }
    if (lane == 0) {
        int n = totM + totT;
        cnt[row] = n;
        dinv[row] = 1.0f / ((float)n + 1e-8f);
    }
}

// ---------------- agg = x + dinv * sum_{j in ell[row]} x[j] ----------------
__global__ __launch_bounds__(256) void spmm_ell_kernel(
        const float* __restrict__ x, const int* __restrict__ ell,
        const int* __restrict__ cnt, const float* __restrict__ dinv,
        float* __restrict__ out) {
    int row = blockIdx.x;
    int t = threadIdx.x;
    int w = t >> 6, lane = t & 63;
    const float4* x4 = (const float4*)x;
    const int* ridx = ell + (size_t)row * ELLW;
    int n = cnt[row];
    float4 acc = make_float4(0.f, 0.f, 0.f, 0.f);
    int i = w;
    for (; i + 12 < n; i += 16) {
        int j0 = ridx[i];
        int j1 = ridx[i + 4];
        int j2 = ridx[i + 8];
        int j3 = ridx[i + 12];
        float4 a0 = x4[(size_t)j0 * 64 + lane];
        float4 a1 = x4[(size_t)j1 * 64 + lane];
        float4 a2 = x4[(size_t)j2 * 64 + lane];
        float4 a3 = x4[(size_t)j3 * 64 + lane];
        acc.x += (a0.x + a1.x) + (a2.x + a3.x);
        acc.y += (a0.y + a1.y) + (a2.y + a3.y);
        acc.z += (a0.z + a1.z) + (a2.z + a3.z);
        acc.w += (a0.w + a1.w) + (a2.w + a3.w);
    }
    for (; i < n; i += 4) {
        float4 a = x4[(size_t)ridx[i] * 64 + lane];
        acc.x += a.x; acc.y += a.y; acc.z += a.z; acc.w += a.w;
    }
    __shared__ float4 part[4][64];
    part[w][lane] = acc;
    __syncthreads();
    const float* pf = (const float*)part;
    float s = (pf[t] + pf[256 + t]) + (pf[512 + t] + pf[768 + t]);
    size_t o = (size_t)row * 256 + t;
    out[o] = x[o] + dinv[row] * s;
}

// ---------------- big GEMM: 128x128 tile, 8x8/thread, reg-prefetch ----------
// Y[N,Mcols] = act(X[N,K] @ W[Mcols,K]^T + b). Requires rows%128==0,
// Mcols%128==0, K%32==0.
// Per k per wave: 4 ds_read_b128 -> 64 FMA (LDS-pipe bound at ~67% VALU).
template<bool RELU>
__global__ __launch_bounds__(256) void gemm128_kernel(
        const float* __restrict__ X, const float* __restrict__ W,
        const float* __restrict__ bias, float* __restrict__ Y,
        int K, int Mcols) {
    const int BK = 32, LDP = 132;   // 128 + 4: keeps b128 16B alignment
    __shared__ float Xs[BK * LDP];
    __shared__ float Ws[BK * LDP];
    int tid = threadIdx.x;
    int row0 = blockIdx.x * 128;
    int col0 = blockIdx.y * 128;
    int tx = tid & 15, ty = tid >> 4;
    float acc[8][8] = {};

    int rr = tid >> 3;              // 0..31 (+32*i)
    int kk = (tid & 7) << 2;        // 0,4,...,28
    float4 rx[4], rw[4];
    #pragma unroll
    for (int i = 0; i < 4; ++i) {
        int r = rr + 32 * i;
        rx[i] = *(const float4*)&X[(size_t)(row0 + r) * K + kk];
        rw[i] = *(const float4*)&W[(size_t)(col0 + r) * K + kk];
    }
    int nchunks = K / BK;
    for (int c = 0; c < nchunks; ++c) {
        #pragma unroll
        for (int i = 0; i < 4; ++i) {
            int r = rr + 32 * i;
            Xs[(kk + 0) * LDP + r] = rx[i].x;
            Xs[(kk + 1) * LDP + r] = rx[i].y;
            Xs[(kk + 2) * LDP + r] = rx[i].z;
            Xs[(kk + 3) * LDP + r] = rx[i].w;
            Ws[(kk + 0) * LDP + r] = rw[i].x;
            Ws[(kk + 1) * LDP + r] = rw[i].y;
            Ws[(kk + 2) * LDP + r] = rw[i].z;
            Ws[(kk + 3) * LDP + r] = rw[i].w;
        }
        __syncthreads();
        if (c + 1 < nchunks) {
            int k0 = (c + 1) * BK + kk;
            #pragma unroll
            for (int i = 0; i < 4; ++i) {
                int r = rr + 32 * i;
                rx[i] = *(const float4*)&X[(size_t)(row0 + r) * K + k0];
                rw[i] = *(const float4*)&W[(size_t)(col0 + r) * K + k0];
            }
        }
        #pragma unroll
        for (int k = 0; k < BK; ++k) {
            float4 a0 = *(const float4*)&Xs[k * LDP + (ty << 3)];
            float4 a1 = *(const float4*)&Xs[k * LDP + (ty << 3) + 4];
            float4 b0 = *(const float4*)&Ws[k * LDP + (tx << 3)];
            float4 b1 = *(const float4*)&Ws[k * LDP + (tx << 3) + 4];
            float av[8] = {a0.x, a0.y, a0.z, a0.w, a1.x, a1.y, a1.z, a1.w};
            float bv[8] = {b0.x, b0.y, b0.z, b0.w, b1.x, b1.y, b1.z, b1.w};
            #pragma unroll
            for (int i2 = 0; i2 < 8; ++i2)
                #pragma unroll
                for (int j2 = 0; j2 < 8; ++j2)
                    acc[i2][j2] += av[i2] * bv[j2];
        }
        __syncthreads();
    }
    float4 bb0 = *(const float4*)&bias[col0 + (tx << 3)];
    float4 bb1 = *(const float4*)&bias[col0 + (tx << 3) + 4];
    float bb[8] = {bb0.x, bb0.y, bb0.z, bb0.w, bb1.x, bb1.y, bb1.z, bb1.w};
    #pragma unroll
    for (int i2 = 0; i2 < 8; ++i2) {
        int row = row0 + (ty << 3) + i2;
        float4 v0, v1;
        float* vp0 = (float*)&v0;
        float* vp1 = (float*)&v1;
        #pragma unroll
        for (int j2 = 0; j2 < 4; ++j2) {
            float t0 = acc[i2][j2] + bb[j2];
            float t1 = acc[i2][j2 + 4] + bb[j2 + 4];
            if (RELU) { t0 = fmaxf(t0, 0.0f); t1 = fmaxf(t1, 0.0f); }
            vp0[j2] = t0;
            vp1[j2] = t1;
        }
        float* yp = &Y[(size_t)row * Mcols + col0 + (tx << 3)];
        *(float4*)yp = v0;
        *(float4*)(yp + 4) = v1;
    }
}

// ---------------- legacy 64x64 tile GEMM (for M=64 head) ----------------
template<bool RELU>
__global__ __launch_bounds__(256) void gemm_kernel(
        const float* __restrict__ X, const float* __restrict__ W,
        const float* __restrict__ bias, float* __restrict__ Y,
        int K, int Mcols) {
    const int BK = 32, LDP = 68;
    __shared__ float Xs[BK * LDP];
    __shared__ float Ws[BK * LDP];
    int tid = threadIdx.x;
    int row0 = blockIdx.x * 64;
    int col0 = blockIdx.y * 64;
    int tx = tid & 15, ty = tid >> 4;
    float acc[4][4] = {};
    for (int k0 = 0; k0 < K; k0 += BK) {
        #pragma unroll
        for (int i = 0; i < 2; ++i) {
            int f = tid + i * 256;
            int r = f >> 3;
            int kk = (f & 7) << 2;
            float4 vx = *(const float4*)&X[(size_t)(row0 + r) * K + k0 + kk];
            float4 vw = *(const float4*)&W[(size_t)(col0 + r) * K + k0 + kk];
            Xs[(kk + 0) * LDP + r] = vx.x;
            Xs[(kk + 1) * LDP + r] = vx.y;
            Xs[(kk + 2) * LDP + r] = vx.z;
            Xs[(kk + 3) * LDP + r] = vx.w;
            Ws[(kk + 0) * LDP + r] = vw.x;
            Ws[(kk + 1) * LDP + r] = vw.y;
            Ws[(kk + 2) * LDP + r] = vw.z;
            Ws[(kk + 3) * LDP + r] = vw.w;
        }
        __syncthreads();
        #pragma unroll
        for (int k = 0; k < BK; ++k) {
            float4 a = *(const float4*)&Xs[k * LDP + (ty << 2)];
            float4 b = *(const float4*)&Ws[k * LDP + (tx << 2)];
            float av[4] = {a.x, a.y, a.z, a.w};
            float bv[4] = {b.x, b.y, b.z, b.w};
            #pragma unroll
            for (int i2 = 0; i2 < 4; ++i2)
                #pragma unroll
                for (int j2 = 0; j2 < 4; ++j2)
                    acc[i2][j2] += av[i2] * bv[j2];
        }
        __syncthreads();
    }
    float4 b4 = *(const float4*)&bias[col0 + (tx << 2)];
    float bb[4] = {b4.x, b4.y, b4.z, b4.w};
    #pragma unroll
    for (int i2 = 0; i2 < 4; ++i2) {
        int row = row0 + (ty << 2) + i2;
        float4 v;
        float* vp = (float*)&v;
        #pragma unroll
        for (int j2 = 0; j2 < 4; ++j2) {
            float tv = acc[i2][j2] + bb[j2];
            if (RELU) tv = fmaxf(tv, 0.0f);
            vp[j2] = tv;
        }
        *(float4*)&Y[(size_t)row * Mcols + col0 + (tx << 2)] = v;
    }
}

// tiny head: Y[N,M] = X[N,K] @ W[M,K]^T + b, K<=64, M small (8)
__global__ void gemm_small_kernel(const float* __restrict__ X, const float* __restrict__ W,
                                  const float* __restrict__ bias, float* __restrict__ Y,
                                  int N, int K, int M) {
    int idx = blockIdx.x * blockDim.x + threadIdx.x;
    if (idx >= N * M) return;
    int r = idx / M, m = idx % M;
    float s = bias[m];
    const float* xr = X + (size_t)r * K;
    const float* wr = W + (size_t)m * K;
    for (int k = 0; k < K; ++k) s += xr[k] * wr[k];
    Y[idx] = s;
}

__global__ void col_mean_kernel(const float* __restrict__ ne, float* __restrict__ gf, int N, int D) {
    int t = threadIdx.x;   // 0..127
    float s = 0.0f;
    for (int r = blockIdx.x; r < N; r += gridDim.x) s += ne[(size_t)r * D + t];
    atomicAdd(&gf[t], s * (1.0f / (float)N));
}

extern "C" void kernel_launch(void* const* d_in, const int* in_sizes, int n_in,
                              void* d_out, int out_size, void* d_ws, size_t ws_size,
                              hipStream_t stream) {
    const int N = NNODES, H = 256;
    const float* nf     = (const float*)d_in[0];
    const int*   ei     = (const int*)d_in[1];
    const float* enc_w1 = (const float*)d_in[2];
    const float* enc_b1 = (const float*)d_in[3];
    const float* enc_w2 = (const float*)d_in[4];
    const float* enc_b2 = (const float*)d_in[5];
    const float* gin_w  = (const float*)d_in[6];
    const float* gin_b  = (const float*)d_in[7];
    const float* gl_w   = (const float*)d_in[8];
    const float* gl_b   = (const float*)d_in[9];
    const float* gout_w = (const float*)d_in[10];
    const float* gout_b = (const float*)d_in[11];
    const float* proj_w = (const float*)d_in[12];
    const float* proj_b = (const float*)d_in[13];
    const float* hc_w1  = (const float*)d_in[14];
    const float* hc_b1  = (const float*)d_in[15];
    const float* hc_w2  = (const float*)d_in[16];
    const float* hc_b2  = (const float*)d_in[17];
    const int E = in_sizes[1] >> 1;

    // workspace carve:
    // [0, 37.75MB): masks M,MT -- dead after ell_fill; ALIASED by bufA/B/C after
    // [37.75MB, ...): ell (12.58MB), cnt, dinv  -- live for whole launch
    char* ws = (char*)d_ws;
    u64* M  = (u64*)ws;
    u64* MT = M + (size_t)N * WORDS;
    int* ell = (int*)(MT + (size_t)N * WORDS);
    int* cntb = ell + (size_t)N * ELLW;
    float* dinv = (float*)(cntb + N);
    float* bufA = (float*)ws;              // aliases M/MT (3*12.58MB == 2*18.87MB)
    float* bufB = bufA + (size_t)N * H;
    float* bufC = bufB + (size_t)N * H;

    float* ne     = (float*)d_out;                        // [N,128]
    float* logits = ne + (size_t)N * 128;                 // [N,8]
    float* gf     = logits + (size_t)N * 8;               // [128]

    hipMemsetAsync(M, 0, 2 * (size_t)N * WORDS * sizeof(u64), stream);
    hipMemsetAsync(gf, 0, 128 * sizeof(float), stream);

    build_mask_kernel<<<(E + 255) / 256, 256, 0, stream>>>(ei, M, MT, E);
    ell_fill_kernel<<<N / 4, 256, 0, stream>>>(M, MT, ell, cntb, dinv);
    // masks dead from here; bufA/B/C may clobber them

    dim3 g128(N / 128, 2);   // 256 output cols
    gemm128_kernel<true ><<<g128, 256, 0, stream>>>(nf,   enc_w1, enc_b1, bufA, 256, 256);
    gemm128_kernel<false><<<g128, 256, 0, stream>>>(bufA, enc_w2, enc_b2, bufB, 256, 256);
    gemm128_kernel<true ><<<g128, 256, 0, stream>>>(bufB, gin_w, gin_b, bufA, 256, 256);

    float* cur = bufA;
    float* nxt = bufB;
    for (int i = 0; i < 3; ++i) {
        spmm_ell_kernel<<<N, 256, 0, stream>>>(cur, ell, cntb, dinv, bufC);
        gemm128_kernel<true><<<g128, 256, 0, stream>>>(bufC, gl_w + (size_t)i * H * H,
                                                       gl_b + (size_t)i * H, nxt, 256, 256);
        float* tmp = cur; cur = nxt; nxt = tmp;
    }
    gemm128_kernel<false><<<g128, 256, 0, stream>>>(cur, gout_w, gout_b, nxt, 256, 256);
    // ne = relu(x @ proj_w^T + proj_b)   [N,128]
    gemm128_kernel<true ><<<dim3(N / 128, 1), 256, 0, stream>>>(nxt, proj_w, proj_b, ne, 256, 128);
    // t = relu(ne @ hc_w1^T + hc_b1)     [N,64] (M=64 -> legacy 64x64 kernel)
    gemm_kernel<true ><<<dim3(N / 64, 1), 256, 0, stream>>>(ne, hc_w1, hc_b1, bufC, 128, 64);
    gemm_small_kernel<<<(N * 8 + 255) / 256, 256, 0, stream>>>(bufC, hc_w2, hc_b2, logits, N, 64, 8);
    col_mean_kernel<<<192, 128, 0, stream>>>(ne, gf, N, 128);
}

// Round 4
// 524.448 us; speedup vs baseline: 1.3257x; 1.3257x over previous
//
#include <hip/hip_runtime.h>

typedef unsigned long long u64;
typedef unsigned short ushort_t;
typedef unsigned int uint32;

#define NNODES 12288
#define WORDS 192   // 12288 / 64 bits per row
#define ELLW 256    // max neighbors per row (avg 64, Poisson tail safe)

typedef __attribute__((ext_vector_type(8))) short short8_t;   // 8 bf16 (4 VGPRs)
typedef __attribute__((ext_vector_type(4))) float f32x4;      // MFMA C/D frag

// ---- bf16 split helpers (RNE) ----
__device__ __forceinline__ ushort_t f2bf(float f) {
    uint32 u = __float_as_uint(f);
    return (ushort_t)((u + 0x7fffu + ((u >> 16) & 1u)) >> 16);
}
__device__ __forceinline__ float bf2f(ushort_t h) {
    return __uint_as_float(((uint32)h) << 16);
}

// ---------------- adjacency build: bitmask M[s][d], MT[d][s] ----------------
__global__ void build_mask_kernel(const int* __restrict__ ei, u64* __restrict__ M,
                                  u64* __restrict__ MT, int E) {
    int e = blockIdx.x * blockDim.x + threadIdx.x;
    if (e >= E) return;
    int s = ei[e];
    int d = ei[E + e];
    atomicOr(&M[(size_t)s * WORDS + (d >> 6)], 1ull << (d & 63));
    atomicOr(&MT[(size_t)d * WORDS + (s >> 6)], 1ull << (s & 63));
}

// ---------------- bitmask -> ELL neighbor list + cnt + dinv ----------------
__global__ __launch_bounds__(256) void ell_fill_kernel(
        const u64* __restrict__ M, const u64* __restrict__ MT,
        int* __restrict__ ell, int* __restrict__ cnt, float* __restrict__ dinv) {
    int row = blockIdx.x * 4 + (threadIdx.x >> 6);
    int lane = threadIdx.x & 63;
    const u64* rM  = M  + (size_t)row * WORDS;
    const u64* rMT = MT + (size_t)row * WORDS;
    u64 wm[3], wt[3];
    int pm = 0, pt = 0;
    #pragma unroll
    for (int k = 0; k < 3; ++k) {
        wm[k] = rM[lane + 64 * k];  pm += __popcll(wm[k]);
        wt[k] = rMT[lane + 64 * k]; pt += __popcll(wt[k]);
    }
    int inclM = pm, inclT = pt;
    #pragma unroll
    for (int off = 1; off < 64; off <<= 1) {
        int ym = __shfl_up(inclM, off, 64);
        int yt = __shfl_up(inclT, off, 64);
        if (lane >= off) { inclM += ym; inclT += yt; }
    }
    int exclM = inclM - pm;
    int exclT = inclT - pt;
    int totM = __shfl(inclM, 63, 64);
    int totT = __shfl(inclT, 63, 64);
    int* out = ell + (size_t)row * ELLW;
    int pos = exclM;
    #pragma unroll
    for (int k = 0; k < 3; ++k) {
        u64 bits = wm[k];
        int base = (lane + 64 * k) << 6;
        while (bits) { out[pos++] = base + __builtin_ctzll(bits); bits &= bits - 1; }
    }
    pos = totM + exclT;
    #pragma unroll
    for (int k = 0; k < 3; ++k) {
        u64 bits = wt[k];
        int base = (lane + 64 * k) << 6;
        while (bits) { out[pos++] = base + __builtin_ctzll(bits); bits &= bits - 1; }
    }
    if (lane == 0) {
        int n = totM + totT;
        cnt[row] = n;
        dinv[row] = 1.0f / ((float)n + 1e-8f);
    }
}

// ---------------- weight prep: split all GEMM weights into bf16 hi/lo -------
// arena layout (elements): enc1 0 | enc2 65536 | gin 131072 | gl 196608(x3) |
//                          gout 393216 | proj 458752 | total 491520
__global__ void wprep_kernel(const float* __restrict__ e1, const float* __restrict__ e2,
                             const float* __restrict__ gi, const float* __restrict__ gl,
                             const float* __restrict__ go, const float* __restrict__ pj,
                             ushort_t* __restrict__ hi, ushort_t* __restrict__ lo) {
    int i = blockIdx.x * 256 + threadIdx.x;
    if (i >= 491520) return;
    float v;
    if (i < 131072)      v = (i < 65536) ? e1[i] : e2[i - 65536];
    else if (i < 196608) v = gi[i - 131072];
    else if (i < 393216) v = gl[i - 196608];
    else if (i < 458752) v = go[i - 393216];
    else                 v = pj[i - 458752];
    ushort_t h = f2bf(v);
    hi[i] = h;
    lo[i] = f2bf(v - bf2f(h));
}

// ---------------- generic fp32 -> bf16 hi/lo split (vectorized) ----------------
__global__ void conv_split_kernel(const float* __restrict__ src, ushort_t* __restrict__ hi,
                                  ushort_t* __restrict__ lo, int n4) {
    int i = blockIdx.x * 256 + threadIdx.x;
    if (i >= n4) return;
    float4 v = ((const float4*)src)[i];
    ushort_t h0 = f2bf(v.x), h1 = f2bf(v.y), h2 = f2bf(v.z), h3 = f2bf(v.w);
    ushort4 hv = make_ushort4(h0, h1, h2, h3);
    ushort4 lv = make_ushort4(f2bf(v.x - bf2f(h0)), f2bf(v.y - bf2f(h1)),
                              f2bf(v.z - bf2f(h2)), f2bf(v.w - bf2f(h3)));
    ((ushort4*)hi)[i] = hv;
    ((ushort4*)lo)[i] = lv;
}

// ---------------- agg = x + dinv * sum_{j in ell[row]} x[j]; out = bf16 hi/lo ----
__global__ __launch_bounds__(256) void spmm_ell_kernel(
        const float* __restrict__ x, const int* __restrict__ ell,
        const int* __restrict__ cnt, const float* __restrict__ dinv,
        ushort_t* __restrict__ outh, ushort_t* __restrict__ outl) {
    int row = blockIdx.x;
    int t = threadIdx.x;
    int w = t >> 6, lane = t & 63;
    const float4* x4 = (const float4*)x;
    const int* ridx = ell + (size_t)row * ELLW;
    int n = cnt[row];
    float4 acc = make_float4(0.f, 0.f, 0.f, 0.f);
    int i = w;
    for (; i + 12 < n; i += 16) {
        int j0 = ridx[i];
        int j1 = ridx[i + 4];
        int j2 = ridx[i + 8];
        int j3 = ridx[i + 12];
        float4 a0 = x4[(size_t)j0 * 64 + lane];
        float4 a1 = x4[(size_t)j1 * 64 + lane];
        float4 a2 = x4[(size_t)j2 * 64 + lane];
        float4 a3 = x4[(size_t)j3 * 64 + lane];
        acc.x += (a0.x + a1.x) + (a2.x + a3.x);
        acc.y += (a0.y + a1.y) + (a2.y + a3.y);
        acc.z += (a0.z + a1.z) + (a2.z + a3.z);
        acc.w += (a0.w + a1.w) + (a2.w + a3.w);
    }
    for (; i < n; i += 4) {
        float4 a = x4[(size_t)ridx[i] * 64 + lane];
        acc.x += a.x; acc.y += a.y; acc.z += a.z; acc.w += a.w;
    }
    __shared__ float4 part[4][64];
    part[w][lane] = acc;
    __syncthreads();
    const float* pf = (const float*)part;
    float sacc = (pf[t] + pf[256 + t]) + (pf[512 + t] + pf[768 + t]);
    size_t o = (size_t)row * 256 + t;
    float s = x[o] + dinv[row] * sacc;
    ushort_t h = f2bf(s);
    outh[o] = h;
    outl[o] = f2bf(s - bf2f(h));
}

// ---------------- split-bf16 MFMA GEMM ----------------
// Y[N,Mcols] = act(X @ W^T + b),  X split (Xhi,Xlo)[N,K] bf16, W split [Mcols,K] bf16.
// Y = Xhi Whi^T + Xhi Wlo^T + Xlo Whi^T  (lo*lo dropped, ~2^-18 relative)
// 128x128 tile, BK=32, 4 waves (one 64x64 quadrant each), 16x16x32 MFMA,
// double-buffered LDS (64KB) staged via global_load_lds width=16.
__device__ __forceinline__ void stage_tile(const ushort_t* __restrict__ src, int rowbase,
                                           int K, int k0, ushort_t* ldsdst, int w, int lane) {
    #pragma unroll
    for (int i = 0; i < 2; ++i) {
        int c16 = (w * 2 + i) * 64 + lane;           // 16B-chunk id within 8KB tile
        int r = c16 >> 2, q = c16 & 3;
        const ushort_t* gp = src + (size_t)(rowbase + r) * K + k0 + q * 8;
        __builtin_amdgcn_global_load_lds(
            (const __attribute__((address_space(1))) void*)gp,
            (__attribute__((address_space(3))) void*)(ldsdst + (w * 2 + i) * 512),
            16, 0, 0);
    }
}

template<bool RELU, bool F32OUT, bool BF16OUT>
__global__ __launch_bounds__(256) void gemm_mfma_kernel(
        const ushort_t* __restrict__ Xhi, const ushort_t* __restrict__ Xlo,
        const ushort_t* __restrict__ Whi, const ushort_t* __restrict__ Wlo,
        const float* __restrict__ bias, float* __restrict__ Yf,
        ushort_t* __restrict__ Yhi, ushort_t* __restrict__ Ylo,
        int K, int Mcols) {
    __shared__ __align__(16) ushort_t lds[2][4][4096];   // [buf][Ahi,Alo,Bhi,Blo][128*32]
    int tid = threadIdx.x;
    int lane = tid & 63;
    int w = __builtin_amdgcn_readfirstlane(tid >> 6);
    int row0 = blockIdx.x * 128;
    int col0 = blockIdx.y * 128;
    int wr = (w & 1) * 64;      // wave quadrant
    int wc = (w >> 1) * 64;
    int fr = lane & 15, fq = lane >> 4;

    f32x4 acc[4][4];
    #pragma unroll
    for (int a = 0; a < 4; ++a)
        #pragma unroll
        for (int b = 0; b < 4; ++b) {
            f32x4 z = {0.f, 0.f, 0.f, 0.f};
            acc[a][b] = z;
        }

    int NC = K >> 5;
    // prologue: stage chunk 0 -> buf 0
    stage_tile(Xhi, row0, K, 0, &lds[0][0][0], w, lane);
    stage_tile(Xlo, row0, K, 0, &lds[0][1][0], w, lane);
    stage_tile(Whi, col0, K, 0, &lds[0][2][0], w, lane);
    stage_tile(Wlo, col0, K, 0, &lds[0][3][0], w, lane);
    __syncthreads();

    for (int c = 0; c < NC; ++c) {
        int bb = c & 1;
        if (c + 1 < NC) {
            int nb = (c + 1) & 1, k0 = (c + 1) << 5;
            stage_tile(Xhi, row0, K, k0, &lds[nb][0][0], w, lane);
            stage_tile(Xlo, row0, K, k0, &lds[nb][1][0], w, lane);
            stage_tile(Whi, col0, K, k0, &lds[nb][2][0], w, lane);
            stage_tile(Wlo, col0, K, k0, &lds[nb][3][0], w, lane);
        }
        const ushort_t* Ah = &lds[bb][0][0];
        const ushort_t* Al = &lds[bb][1][0];
        const ushort_t* Bh = &lds[bb][2][0];
        const ushort_t* Bl = &lds[bb][3][0];
        short8_t ah[4], al[4], bh[4], bl[4];
        #pragma unroll
        for (int t4 = 0; t4 < 4; ++t4) {
            int ao = (wr + 16 * t4 + fr) * 32 + fq * 8;
            int bo = (wc + 16 * t4 + fr) * 32 + fq * 8;
            ah[t4] = *(const short8_t*)&Ah[ao];
            al[t4] = *(const short8_t*)&Al[ao];
            bh[t4] = *(const short8_t*)&Bh[bo];
            bl[t4] = *(const short8_t*)&Bl[bo];
        }
        #pragma unroll
        for (int mt = 0; mt < 4; ++mt)
            #pragma unroll
            for (int nt = 0; nt < 4; ++nt) {
                f32x4 a = acc[mt][nt];
                a = __builtin_amdgcn_mfma_f32_16x16x32_bf16(ah[mt], bh[nt], a, 0, 0, 0);
                a = __builtin_amdgcn_mfma_f32_16x16x32_bf16(ah[mt], bl[nt], a, 0, 0, 0);
                a = __builtin_amdgcn_mfma_f32_16x16x32_bf16(al[mt], bh[nt], a, 0, 0, 0);
                acc[mt][nt] = a;
            }
        __syncthreads();
    }

    // epilogue: bias + act + store (C/D: col = lane&15, row = (lane>>4)*4 + reg)
    float bcol[4];
    #pragma unroll
    for (int nt = 0; nt < 4; ++nt) bcol[nt] = bias[col0 + wc + 16 * nt + fr];
    #pragma unroll
    for (int mt = 0; mt < 4; ++mt) {
        int gr0 = row0 + wr + 16 * mt + fq * 4;
        #pragma unroll
        for (int nt = 0; nt < 4; ++nt) {
            int gc = col0 + wc + 16 * nt + fr;
            #pragma unroll
            for (int e = 0; e < 4; ++e) {
                float v = acc[mt][nt][e] + bcol[nt];
                if (RELU) v = fmaxf(v, 0.0f);
                size_t off = (size_t)(gr0 + e) * Mcols + gc;
                if (F32OUT) Yf[off] = v;
                if (BF16OUT) {
                    ushort_t h = f2bf(v);
                    Yhi[off] = h;
                    Ylo[off] = f2bf(v - bf2f(h));
                }
            }
        }
    }
}

// ---------------- legacy fp32 64x64 GEMM (hc1 head: K=128, M=64) ----------------
template<bool RELU>
__global__ __launch_bounds__(256) void gemm_kernel(
        const float* __restrict__ X, const float* __restrict__ W,
        const float* __restrict__ bias, float* __restrict__ Y,
        int K, int Mcols) {
    const int BK = 32, LDP = 68;
    __shared__ float Xs[BK * LDP];
    __shared__ float Ws[BK * LDP];
    int tid = threadIdx.x;
    int row0 = blockIdx.x * 64;
    int col0 = blockIdx.y * 64;
    int tx = tid & 15, ty = tid >> 4;
    float acc[4][4] = {};
    for (int k0 = 0; k0 < K; k0 += BK) {
        #pragma unroll
        for (int i = 0; i < 2; ++i) {
            int f = tid + i * 256;
            int r = f >> 3;
            int kk = (f & 7) << 2;
            float4 vx = *(const float4*)&X[(size_t)(row0 + r) * K + k0 + kk];
            float4 vw = *(const float4*)&W[(size_t)(col0 + r) * K + k0 + kk];
            Xs[(kk + 0) * LDP + r] = vx.x;
            Xs[(kk + 1) * LDP + r] = vx.y;
            Xs[(kk + 2) * LDP + r] = vx.z;
            Xs[(kk + 3) * LDP + r] = vx.w;
            Ws[(kk + 0) * LDP + r] = vw.x;
            Ws[(kk + 1) * LDP + r] = vw.y;
            Ws[(kk + 2) * LDP + r] = vw.z;
            Ws[(kk + 3) * LDP + r] = vw.w;
        }
        __syncthreads();
        #pragma unroll
        for (int k = 0; k < BK; ++k) {
            float4 a = *(const float4*)&Xs[k * LDP + (ty << 2)];
            float4 b = *(const float4*)&Ws[k * LDP + (tx << 2)];
            float av[4] = {a.x, a.y, a.z, a.w};
            float bv[4] = {b.x, b.y, b.z, b.w};
            #pragma unroll
            for (int i2 = 0; i2 < 4; ++i2)
                #pragma unroll
                for (int j2 = 0; j2 < 4; ++j2)
                    acc[i2][j2] += av[i2] * bv[j2];
        }
        __syncthreads();
    }
    float4 b4 = *(const float4*)&bias[col0 + (tx << 2)];
    float bb[4] = {b4.x, b4.y, b4.z, b4.w};
    #pragma unroll
    for (int i2 = 0; i2 < 4; ++i2) {
        int row = row0 + (ty << 2) + i2;
        float4 v;
        float* vp = (float*)&v;
        #pragma unroll
        for (int j2 = 0; j2 < 4; ++j2) {
            float tv = acc[i2][j2] + bb[j2];
            if (RELU) tv = fmaxf(tv, 0.0f);
            vp[j2] = tv;
        }
        *(float4*)&Y[(size_t)row * Mcols + col0 + (tx << 2)] = v;
    }
}

// tiny head: Y[N,M] = X[N,K] @ W[M,K]^T + b, K<=64, M small (8)
__global__ void gemm_small_kernel(const float* __restrict__ X, const float* __restrict__ W,
                                  const float* __restrict__ bias, float* __restrict__ Y,
                                  int N, int K, int M) {
    int idx = blockIdx.x * blockDim.x + threadIdx.x;
    if (idx >= N * M) return;
    int r = idx / M, m = idx % M;
    float s = bias[m];
    const float* xr = X + (size_t)r * K;
    const float* wr = W + (size_t)m * K;
    for (int k = 0; k < K; ++k) s += xr[k] * wr[k];
    Y[idx] = s;
}

__global__ void col_mean_kernel(const float* __restrict__ ne, float* __restrict__ gf, int N, int D) {
    int t = threadIdx.x;   // 0..127
    float s = 0.0f;
    for (int r = blockIdx.x; r < N; r += gridDim.x) s += ne[(size_t)r * D + t];
    atomicAdd(&gf[t], s * (1.0f / (float)N));
}

extern "C" void kernel_launch(void* const* d_in, const int* in_sizes, int n_in,
                              void* d_out, int out_size, void* d_ws, size_t ws_size,
                              hipStream_t stream) {
    const int N = NNODES;
    const float* nf     = (const float*)d_in[0];
    const int*   ei     = (const int*)d_in[1];
    const float* enc_w1 = (const float*)d_in[2];
    const float* enc_b1 = (const float*)d_in[3];
    const float* enc_w2 = (const float*)d_in[4];
    const float* enc_b2 = (const float*)d_in[5];
    const float* gin_w  = (const float*)d_in[6];
    const float* gin_b  = (const float*)d_in[7];
    const float* gl_w   = (const float*)d_in[8];
    const float* gl_b   = (const float*)d_in[9];
    const float* gout_w = (const float*)d_in[10];
    const float* gout_b = (const float*)d_in[11];
    const float* proj_w = (const float*)d_in[12];
    const float* proj_b = (const float*)d_in[13];
    const float* hc_w1  = (const float*)d_in[14];
    const float* hc_b1  = (const float*)d_in[15];
    const float* hc_w2  = (const float*)d_in[16];
    const float* hc_b2  = (const float*)d_in[17];
    const int E = in_sizes[1] >> 1;

    // workspace carve (bytes):
    // [0, 37748736): masks M(18.9M)+MT(18.9M) -- dead after ell_fill; then
    //                aliased by xf(12.6M f32) + pairA hi/lo + pairB hi/lo (4x6.3M bf16)
    // [37748736, 50331648): ell
    // then cnt, dinv, Whi arena, Wlo arena, bufC (hc1 out)
    char* ws = (char*)d_ws;
    u64* M  = (u64*)ws;
    u64* MT = M + (size_t)N * WORDS;
    float*    xf  = (float*)ws;                                 // 12,582,912
    ushort_t* pAh = (ushort_t*)(ws + 12582912);                 //  6,291,456
    ushort_t* pAl = (ushort_t*)(ws + 18874368);
    ushort_t* pBh = (ushort_t*)(ws + 25165824);
    ushort_t* pBl = (ushort_t*)(ws + 31457280);                 // ends 37,748,736
    int*      ell = (int*)(ws + 37748736);                      // 12,582,912
    int*      cntb = (int*)(ws + 50331648);                     //     49,152
    float*    dinv = (float*)(ws + 50380800);                   //     49,152
    ushort_t* Whi  = (ushort_t*)(ws + 50429952);                //    983,040
    ushort_t* Wlo  = (ushort_t*)(ws + 51412992);                //    983,040
    float*    bufC = (float*)(ws + 52396032);                   //  3,145,728

    float* ne     = (float*)d_out;                        // [N,128]
    float* logits = ne + (size_t)N * 128;                 // [N,8]
    float* gf     = logits + (size_t)N * 8;               // [128]

    hipMemsetAsync(M, 0, 2 * (size_t)N * WORDS * sizeof(u64), stream);
    hipMemsetAsync(gf, 0, 128 * sizeof(float), stream);

    build_mask_kernel<<<(E + 255) / 256, 256, 0, stream>>>(ei, M, MT, E);
    ell_fill_kernel<<<N / 4, 256, 0, stream>>>(M, MT, ell, cntb, dinv);
    // masks dead from here; xf/pairA/pairB may clobber them

    wprep_kernel<<<1920, 256, 0, stream>>>(enc_w1, enc_w2, gin_w, gl_w, gout_w, proj_w,
                                           Whi, Wlo);
    conv_split_kernel<<<3072, 256, 0, stream>>>(nf, pBh, pBl, N * 64);   // nf -> pairB

    dim3 g(N / 128, 2);   // 256 output cols
    // enc1: pairB -> pairA (relu, bf16 out)
    gemm_mfma_kernel<true, false, true><<<g, 256, 0, stream>>>(
        pBh, pBl, Whi, Wlo, enc_b1, nullptr, pAh, pAl, 256, 256);
    // enc2: pairA -> pairB (no relu, bf16 out)
    gemm_mfma_kernel<false, false, true><<<g, 256, 0, stream>>>(
        pAh, pAl, Whi + 65536, Wlo + 65536, enc_b2, nullptr, pBh, pBl, 256, 256);
    // gin: pairB -> xf (relu, f32 out)
    gemm_mfma_kernel<true, true, false><<<g, 256, 0, stream>>>(
        pBh, pBl, Whi + 131072, Wlo + 131072, gin_b, xf, nullptr, nullptr, 256, 256);

    for (int i = 0; i < 3; ++i) {
        spmm_ell_kernel<<<N, 256, 0, stream>>>(xf, ell, cntb, dinv, pAh, pAl);
        if (i < 2) {
            gemm_mfma_kernel<true, true, false><<<g, 256, 0, stream>>>(
                pAh, pAl, Whi + 196608 + 65536 * i, Wlo + 196608 + 65536 * i,
                gl_b + 256 * i, xf, nullptr, nullptr, 256, 256);
        } else {
            gemm_mfma_kernel<true, false, true><<<g, 256, 0, stream>>>(
                pAh, pAl, Whi + 196608 + 65536 * i, Wlo + 196608 + 65536 * i,
                gl_b + 256 * i, nullptr, pBh, pBl, 256, 256);
        }
    }
    // gout: pairB -> pairA (no relu, bf16 out)
    gemm_mfma_kernel<false, false, true><<<g, 256, 0, stream>>>(
        pBh, pBl, Whi + 393216, Wlo + 393216, gout_b, nullptr, pAh, pAl, 256, 256);
    // proj: pairA -> ne f32 (relu), M=128
    gemm_mfma_kernel<true, true, false><<<dim3(N / 128, 1), 256, 0, stream>>>(
        pAh, pAl, Whi + 458752, Wlo + 458752, proj_b, ne, nullptr, nullptr, 256, 128);
    // hc1: fp32 legacy (K=128, M=64)
    gemm_kernel<true><<<dim3(N / 64, 1), 256, 0, stream>>>(ne, hc_w1, hc_b1, bufC, 128, 64);
    gemm_small_kernel<<<(N * 8 + 255) / 256, 256, 0, stream>>>(bufC, hc_w2, hc_b2, logits, N, 64, 8);
    col_mean_kernel<<<192, 128, 0, stream>>>(ne, gf, N, 128);
}

// Round 5
// 443.361 us; speedup vs baseline: 1.5682x; 1.1829x over previous
//
#include <hip/hip_runtime.h>

typedef unsigned long long u64;
typedef unsigned short ushort_t;
typedef unsigned int uint32;

#define NNODES 12288
#define WORDS 192   // 12288 / 64 bits per row
#define ELLW 256    // max neighbors per row (avg ~64, Poisson tail safe)
#define CHSZ (NNODES * 64)   // elements per 64-col chunk of x

typedef __attribute__((ext_vector_type(8))) short short8_t;   // 8 bf16 (4 VGPRs)
typedef __attribute__((ext_vector_type(4))) float f32x4;      // MFMA C/D frag

// ---- bf16 split helpers (RNE) ----
__device__ __forceinline__ ushort_t f2bf(float f) {
    uint32 u = __float_as_uint(f);
    return (ushort_t)((u + 0x7fffu + ((u >> 16) & 1u)) >> 16);
}
__device__ __forceinline__ float bf2f(ushort_t h) {
    return __uint_as_float(((uint32)h) << 16);
}

// ---------------- adjacency build: bitmask M[s][d], MT[d][s] ----------------
__global__ void build_mask_kernel(const int* __restrict__ ei, u64* __restrict__ M,
                                  u64* __restrict__ MT, int E) {
    int e = blockIdx.x * blockDim.x + threadIdx.x;
    if (e >= E) return;
    int s = ei[e];
    int d = ei[E + e];
    atomicOr(&M[(size_t)s * WORDS + (d >> 6)], 1ull << (d & 63));
    atomicOr(&MT[(size_t)d * WORDS + (s >> 6)], 1ull << (s & 63));
}

// ---------------- bitmask -> u16 ELL neighbor list + cnt + dinv ----------------
__global__ __launch_bounds__(256) void ell_fill_kernel(
        const u64* __restrict__ M, const u64* __restrict__ MT,
        ushort_t* __restrict__ ell, int* __restrict__ cnt, float* __restrict__ dinv) {
    int row = blockIdx.x * 4 + (threadIdx.x >> 6);
    int lane = threadIdx.x & 63;
    const u64* rM  = M  + (size_t)row * WORDS;
    const u64* rMT = MT + (size_t)row * WORDS;
    u64 wm[3], wt[3];
    int pm = 0, pt = 0;
    #pragma unroll
    for (int k = 0; k < 3; ++k) {
        wm[k] = rM[lane + 64 * k];  pm += __popcll(wm[k]);
        wt[k] = rMT[lane + 64 * k]; pt += __popcll(wt[k]);
    }
    int inclM = pm, inclT = pt;
    #pragma unroll
    for (int off = 1; off < 64; off <<= 1) {
        int ym = __shfl_up(inclM, off, 64);
        int yt = __shfl_up(inclT, off, 64);
        if (lane >= off) { inclM += ym; inclT += yt; }
    }
    int exclM = inclM - pm;
    int exclT = inclT - pt;
    int totM = __shfl(inclM, 63, 64);
    int totT = __shfl(inclT, 63, 64);
    ushort_t* out = ell + (size_t)row * ELLW;
    int pos = exclM;
    #pragma unroll
    for (int k = 0; k < 3; ++k) {
        u64 bits = wm[k];
        int base = (lane + 64 * k) << 6;
        while (bits) { out[pos++] = (ushort_t)(base + __builtin_ctzll(bits)); bits &= bits - 1; }
    }
    pos = totM + exclT;
    #pragma unroll
    for (int k = 0; k < 3; ++k) {
        u64 bits = wt[k];
        int base = (lane + 64 * k) << 6;
        while (bits) { out[pos++] = (ushort_t)(base + __builtin_ctzll(bits)); bits &= bits - 1; }
    }
    if (lane == 0) {
        int n = totM + totT;
        cnt[row] = n;
        dinv[row] = 1.0f / ((float)n + 1e-8f);
    }
}

// ---------------- weight prep: split all GEMM weights into bf16 hi/lo -------
// arena layout (elements): enc1 0 | enc2 65536 | gin 131072 | gl 196608(x3) |
//                          gout 393216 | proj 458752 | total 491520
__global__ void wprep_kernel(const float* __restrict__ e1, const float* __restrict__ e2,
                             const float* __restrict__ gi, const float* __restrict__ gl,
                             const float* __restrict__ go, const float* __restrict__ pj,
                             ushort_t* __restrict__ hi, ushort_t* __restrict__ lo) {
    int i = blockIdx.x * 256 + threadIdx.x;
    if (i >= 491520) return;
    float v;
    if (i < 131072)      v = (i < 65536) ? e1[i] : e2[i - 65536];
    else if (i < 196608) v = gi[i - 131072];
    else if (i < 393216) v = gl[i - 196608];
    else if (i < 458752) v = go[i - 393216];
    else                 v = pj[i - 458752];
    ushort_t h = f2bf(v);
    hi[i] = h;
    lo[i] = f2bf(v - bf2f(h));
}

// ---------------- generic fp32 -> bf16 hi/lo split (vectorized) ----------------
__global__ void conv_split_kernel(const float* __restrict__ src, ushort_t* __restrict__ hi,
                                  ushort_t* __restrict__ lo, int n4) {
    int i = blockIdx.x * 256 + threadIdx.x;
    if (i >= n4) return;
    float4 v = ((const float4*)src)[i];
    ushort_t h0 = f2bf(v.x), h1 = f2bf(v.y), h2 = f2bf(v.z), h3 = f2bf(v.w);
    ushort4 hv = make_ushort4(h0, h1, h2, h3);
    ushort4 lv = make_ushort4(f2bf(v.x - bf2f(h0)), f2bf(v.y - bf2f(h1)),
                              f2bf(v.z - bf2f(h2)), f2bf(v.w - bf2f(h3)));
    ((ushort4*)hi)[i] = hv;
    ((ushort4*)lo)[i] = lv;
}

// ---------------- chunked spmm: agg = x + dinv * sum_{j} x[j], bf16 hi/lo out ---
// x in chunk-major layout xc[4][NNODES][64]. Grid (768, 4): all blocks of a
// chunk run together -> 3.1 MB working set stays per-XCD-L2 resident.
// Wave handles 4 rows x 16 float4-lanes (1KB/gather-instr, 4-deep ILP).
__global__ __launch_bounds__(256) void spmm_chunk_kernel(
        const float* __restrict__ xc, const ushort_t* __restrict__ ell,
        const int* __restrict__ cnt, const float* __restrict__ dinv,
        ushort_t* __restrict__ outh, ushort_t* __restrict__ outl) {
    int chunk = blockIdx.y;
    int t = threadIdx.x;
    int lane = t & 63;
    int w = t >> 6;
    int r = lane >> 4;          // sub-row 0..3
    int c16 = lane & 15;        // float4 within 64-col chunk
    int row = blockIdx.x * 16 + w * 4 + r;
    const float* xb = xc + (size_t)chunk * CHSZ + (c16 << 2);
    int n = cnt[row];
    int nm = max(n, __shfl_xor(n, 16, 64));
    nm = max(nm, __shfl_xor(nm, 32, 64));
    nm = (nm + 3) & ~3;
    const ushort_t* rell = ell + (size_t)row * ELLW;
    float ax = 0.f, ay = 0.f, az = 0.f, aw = 0.f;
    for (int i = 0; i < nm; i += 4) {
        ushort4 jj = *(const ushort4*)&rell[i];
        int j0 = jj.x, j1 = jj.y, j2 = jj.z, j3 = jj.w;
        float p0 = 1.f, p1 = 1.f, p2 = 1.f, p3 = 1.f;
        if (i + 0 >= n) { j0 = 0; p0 = 0.f; }
        if (i + 1 >= n) { j1 = 0; p1 = 0.f; }
        if (i + 2 >= n) { j2 = 0; p2 = 0.f; }
        if (i + 3 >= n) { j3 = 0; p3 = 0.f; }
        float4 v0 = *(const float4*)&xb[(size_t)j0 * 64];
        float4 v1 = *(const float4*)&xb[(size_t)j1 * 64];
        float4 v2 = *(const float4*)&xb[(size_t)j2 * 64];
        float4 v3 = *(const float4*)&xb[(size_t)j3 * 64];
        ax += v0.x * p0 + v1.x * p1 + v2.x * p2 + v3.x * p3;
        ay += v0.y * p0 + v1.y * p1 + v2.y * p2 + v3.y * p3;
        az += v0.z * p0 + v1.z * p1 + v2.z * p2 + v3.z * p3;
        aw += v0.w * p0 + v1.w * p1 + v2.w * p2 + v3.w * p3;
    }
    float4 xr = *(const float4*)&xb[(size_t)row * 64];
    float dv = dinv[row];
    float sx = xr.x + dv * ax;
    float sy = xr.y + dv * ay;
    float sz = xr.z + dv * az;
    float sw = xr.w + dv * aw;
    ushort_t hx = f2bf(sx), hy = f2bf(sy), hz = f2bf(sz), hw = f2bf(sw);
    size_t o = (size_t)row * 256 + (chunk << 6) + (c16 << 2);
    *(ushort4*)&outh[o] = make_ushort4(hx, hy, hz, hw);
    *(ushort4*)&outl[o] = make_ushort4(f2bf(sx - bf2f(hx)), f2bf(sy - bf2f(hy)),
                                       f2bf(sz - bf2f(hz)), f2bf(sw - bf2f(hw)));
}

// ---------------- split-bf16 MFMA GEMM ----------------
// Y = act(X @ W^T + b); X,W split into bf16 hi/lo; lo*lo dropped (~2^-18 rel).
// 128x128 tile, BK=32, 4 waves, 16x16x32 MFMA, dbuf LDS via global_load_lds.
// CHUNKX: f32 output written in chunk-major xc layout for the spmm.
__device__ __forceinline__ void stage_tile(const ushort_t* __restrict__ src, int rowbase,
                                           int K, int k0, ushort_t* ldsdst, int w, int lane) {
    #pragma unroll
    for (int i = 0; i < 2; ++i) {
        int c16 = (w * 2 + i) * 64 + lane;           // 16B-chunk id within 8KB tile
        int r = c16 >> 2, q = c16 & 3;
        const ushort_t* gp = src + (size_t)(rowbase + r) * K + k0 + q * 8;
        __builtin_amdgcn_global_load_lds(
            (const __attribute__((address_space(1))) void*)gp,
            (__attribute__((address_space(3))) void*)(ldsdst + (w * 2 + i) * 512),
            16, 0, 0);
    }
}

template<bool RELU, bool F32OUT, bool BF16OUT, bool CHUNKX>
__global__ __launch_bounds__(256) void gemm_mfma_kernel(
        const ushort_t* __restrict__ Xhi, const ushort_t* __restrict__ Xlo,
        const ushort_t* __restrict__ Whi, const ushort_t* __restrict__ Wlo,
        const float* __restrict__ bias, float* __restrict__ Yf,
        ushort_t* __restrict__ Yhi, ushort_t* __restrict__ Ylo,
        int K, int Mcols) {
    __shared__ __align__(16) ushort_t lds[2][4][4096];   // [buf][Ahi,Alo,Bhi,Blo][128*32]
    int tid = threadIdx.x;
    int lane = tid & 63;
    int w = __builtin_amdgcn_readfirstlane(tid >> 6);
    int row0 = blockIdx.x * 128;
    int col0 = blockIdx.y * 128;
    int wr = (w & 1) * 64;      // wave quadrant
    int wc = (w >> 1) * 64;
    int fr = lane & 15, fq = lane >> 4;

    f32x4 acc[4][4];
    #pragma unroll
    for (int a = 0; a < 4; ++a)
        #pragma unroll
        for (int b = 0; b < 4; ++b) {
            f32x4 z = {0.f, 0.f, 0.f, 0.f};
            acc[a][b] = z;
        }

    int NC = K >> 5;
    stage_tile(Xhi, row0, K, 0, &lds[0][0][0], w, lane);
    stage_tile(Xlo, row0, K, 0, &lds[0][1][0], w, lane);
    stage_tile(Whi, col0, K, 0, &lds[0][2][0], w, lane);
    stage_tile(Wlo, col0, K, 0, &lds[0][3][0], w, lane);
    __syncthreads();

    for (int c = 0; c < NC; ++c) {
        int bb = c & 1;
        if (c + 1 < NC) {
            int nb = (c + 1) & 1, k0 = (c + 1) << 5;
            stage_tile(Xhi, row0, K, k0, &lds[nb][0][0], w, lane);
            stage_tile(Xlo, row0, K, k0, &lds[nb][1][0], w, lane);
            stage_tile(Whi, col0, K, k0, &lds[nb][2][0], w, lane);
            stage_tile(Wlo, col0, K, k0, &lds[nb][3][0], w, lane);
        }
        const ushort_t* Ah = &lds[bb][0][0];
        const ushort_t* Al = &lds[bb][1][0];
        const ushort_t* Bh = &lds[bb][2][0];
        const ushort_t* Bl = &lds[bb][3][0];
        short8_t ah[4], al[4], bh[4], bl[4];
        #pragma unroll
        for (int t4 = 0; t4 < 4; ++t4) {
            int ao = (wr + 16 * t4 + fr) * 32 + fq * 8;
            int bo = (wc + 16 * t4 + fr) * 32 + fq * 8;
            ah[t4] = *(const short8_t*)&Ah[ao];
            al[t4] = *(const short8_t*)&Al[ao];
            bh[t4] = *(const short8_t*)&Bh[bo];
            bl[t4] = *(const short8_t*)&Bl[bo];
        }
        #pragma unroll
        for (int mt = 0; mt < 4; ++mt)
            #pragma unroll
            for (int nt = 0; nt < 4; ++nt) {
                f32x4 a = acc[mt][nt];
                a = __builtin_amdgcn_mfma_f32_16x16x32_bf16(ah[mt], bh[nt], a, 0, 0, 0);
                a = __builtin_amdgcn_mfma_f32_16x16x32_bf16(ah[mt], bl[nt], a, 0, 0, 0);
                a = __builtin_amdgcn_mfma_f32_16x16x32_bf16(al[mt], bh[nt], a, 0, 0, 0);
                acc[mt][nt] = a;
            }
        __syncthreads();
    }

    // epilogue: bias + act + store (C/D: col = lane&15, row = (lane>>4)*4 + reg)
    float bcol[4];
    #pragma unroll
    for (int nt = 0; nt < 4; ++nt) bcol[nt] = bias[col0 + wc + 16 * nt + fr];
    #pragma unroll
    for (int mt = 0; mt < 4; ++mt) {
        int gr0 = row0 + wr + 16 * mt + fq * 4;
        #pragma unroll
        for (int nt = 0; nt < 4; ++nt) {
            int gc = col0 + wc + 16 * nt + fr;
            #pragma unroll
            for (int e = 0; e < 4; ++e) {
                float v = acc[mt][nt][e] + bcol[nt];
                if (RELU) v = fmaxf(v, 0.0f);
                size_t off;
                if (CHUNKX)
                    off = (size_t)(gc >> 6) * CHSZ + (size_t)(gr0 + e) * 64 + (gc & 63);
                else
                    off = (size_t)(gr0 + e) * Mcols + gc;
                if (F32OUT) Yf[off] = v;
                if (BF16OUT) {
                    ushort_t h = f2bf(v);
                    Yhi[off] = h;
                    Ylo[off] = f2bf(v - bf2f(h));
                }
            }
        }
    }
}

// ---------------- legacy fp32 64x64 GEMM (hc1 head: K=128, M=64) ----------------
template<bool RELU>
__global__ __launch_bounds__(256) void gemm_kernel(
        const float* __restrict__ X, const float* __restrict__ W,
        const float* __restrict__ bias, float* __restrict__ Y,
        int K, int Mcols) {
    const int BK = 32, LDP = 68;
    __shared__ float Xs[BK * LDP];
    __shared__ float Ws[BK * LDP];
    int tid = threadIdx.x;
    int row0 = blockIdx.x * 64;
    int col0 = blockIdx.y * 64;
    int tx = tid & 15, ty = tid >> 4;
    float acc[4][4] = {};
    for (int k0 = 0; k0 < K; k0 += BK) {
        #pragma unroll
        for (int i = 0; i < 2; ++i) {
            int f = tid + i * 256;
            int r = f >> 3;
            int kk = (f & 7) << 2;
            float4 vx = *(const float4*)&X[(size_t)(row0 + r) * K + k0 + kk];
            float4 vw = *(const float4*)&W[(size_t)(col0 + r) * K + k0 + kk];
            Xs[(kk + 0) * LDP + r] = vx.x;
            Xs[(kk + 1) * LDP + r] = vx.y;
            Xs[(kk + 2) * LDP + r] = vx.z;
            Xs[(kk + 3) * LDP + r] = vx.w;
            Ws[(kk + 0) * LDP + r] = vw.x;
            Ws[(kk + 1) * LDP + r] = vw.y;
            Ws[(kk + 2) * LDP + r] = vw.z;
            Ws[(kk + 3) * LDP + r] = vw.w;
        }
        __syncthreads();
        #pragma unroll
        for (int k = 0; k < BK; ++k) {
            float4 a = *(const float4*)&Xs[k * LDP + (ty << 2)];
            float4 b = *(const float4*)&Ws[k * LDP + (tx << 2)];
            float av[4] = {a.x, a.y, a.z, a.w};
            float bv[4] = {b.x, b.y, b.z, b.w};
            #pragma unroll
            for (int i2 = 0; i2 < 4; ++i2)
                #pragma unroll
                for (int j2 = 0; j2 < 4; ++j2)
                    acc[i2][j2] += av[i2] * bv[j2];
        }
        __syncthreads();
    }
    float4 b4 = *(const float4*)&bias[col0 + (tx << 2)];
    float bb[4] = {b4.x, b4.y, b4.z, b4.w};
    #pragma unroll
    for (int i2 = 0; i2 < 4; ++i2) {
        int row = row0 + (ty << 2) + i2;
        float4 v;
        float* vp = (float*)&v;
        #pragma unroll
        for (int j2 = 0; j2 < 4; ++j2) {
            float tv = acc[i2][j2] + bb[j2];
            if (RELU) tv = fmaxf(tv, 0.0f);
            vp[j2] = tv;
        }
        *(float4*)&Y[(size_t)row * Mcols + col0 + (tx << 2)] = v;
    }
}

// tiny head: Y[N,M] = X[N,K] @ W[M,K]^T + b, K<=64, M small (8)
__global__ void gemm_small_kernel(const float* __restrict__ X, const float* __restrict__ W,
                                  const float* __restrict__ bias, float* __restrict__ Y,
                                  int N, int K, int M) {
    int idx = blockIdx.x * blockDim.x + threadIdx.x;
    if (idx >= N * M) return;
    int r = idx / M, m = idx % M;
    float s = bias[m];
    const float* xr = X + (size_t)r * K;
    const float* wr = W + (size_t)m * K;
    for (int k = 0; k < K; ++k) s += xr[k] * wr[k];
    Y[idx] = s;
}

__global__ void col_mean_kernel(const float* __restrict__ ne, float* __restrict__ gf, int N, int D) {
    int t = threadIdx.x;   // 0..127
    float s = 0.0f;
    for (int r = blockIdx.x; r < N; r += gridDim.x) s += ne[(size_t)r * D + t];
    atomicAdd(&gf[t], s * (1.0f / (float)N));
}

extern "C" void kernel_launch(void* const* d_in, const int* in_sizes, int n_in,
                              void* d_out, int out_size, void* d_ws, size_t ws_size,
                              hipStream_t stream) {
    const int N = NNODES;
    const float* nf     = (const float*)d_in[0];
    const int*   ei     = (const int*)d_in[1];
    const float* enc_w1 = (const float*)d_in[2];
    const float* enc_b1 = (const float*)d_in[3];
    const float* enc_w2 = (const float*)d_in[4];
    const float* enc_b2 = (const float*)d_in[5];
    const float* gin_w  = (const float*)d_in[6];
    const float* gin_b  = (const float*)d_in[7];
    const float* gl_w   = (const float*)d_in[8];
    const float* gl_b   = (const float*)d_in[9];
    const float* gout_w = (const float*)d_in[10];
    const float* gout_b = (const float*)d_in[11];
    const float* proj_w = (const float*)d_in[12];
    const float* proj_b = (const float*)d_in[13];
    const float* hc_w1  = (const float*)d_in[14];
    const float* hc_b1  = (const float*)d_in[15];
    const float* hc_w2  = (const float*)d_in[16];
    const float* hc_b2  = (const float*)d_in[17];
    const int E = in_sizes[1] >> 1;

    // workspace carve (bytes):
    // [0, 37748736): masks M+MT -- dead after ell_fill; then aliased by
    //                xc (chunk-major f32, 12.6M) + pairA/pairB hi/lo (4x6.3M bf16)
    // [37748736, ...): ell u16 (6.3M), cnt, dinv, W arenas, bufC
    char* ws = (char*)d_ws;
    u64* M  = (u64*)ws;
    u64* MT = M + (size_t)N * WORDS;
    float*    xc  = (float*)ws;                                 // 12,582,912
    ushort_t* pAh = (ushort_t*)(ws + 12582912);                 //  6,291,456
    ushort_t* pAl = (ushort_t*)(ws + 18874368);
    ushort_t* pBh = (ushort_t*)(ws + 25165824);
    ushort_t* pBl = (ushort_t*)(ws + 31457280);                 // ends 37,748,736
    ushort_t* ell = (ushort_t*)(ws + 37748736);                 //  6,291,456
    int*      cntb = (int*)(ws + 44040192);                     //     49,152
    float*    dinv = (float*)(ws + 44089344);                   //     49,152
    ushort_t* Whi  = (ushort_t*)(ws + 44138496);                //    983,040
    ushort_t* Wlo  = (ushort_t*)(ws + 45121536);                //    983,040
    float*    bufC = (float*)(ws + 46104576);                   //  3,145,728

    float* ne     = (float*)d_out;                        // [N,128]
    float* logits = ne + (size_t)N * 128;                 // [N,8]
    float* gf     = logits + (size_t)N * 8;               // [128]

    hipMemsetAsync(M, 0, 2 * (size_t)N * WORDS * sizeof(u64), stream);
    hipMemsetAsync(gf, 0, 128 * sizeof(float), stream);

    build_mask_kernel<<<(E + 255) / 256, 256, 0, stream>>>(ei, M, MT, E);
    ell_fill_kernel<<<N / 4, 256, 0, stream>>>(M, MT, ell, cntb, dinv);
    // masks dead from here; xc/pairA/pairB may clobber them

    wprep_kernel<<<1920, 256, 0, stream>>>(enc_w1, enc_w2, gin_w, gl_w, gout_w, proj_w,
                                           Whi, Wlo);
    conv_split_kernel<<<3072, 256, 0, stream>>>(nf, pBh, pBl, N * 64);   // nf -> pairB

    dim3 g(N / 128, 2);   // 256 output cols
    // enc1: pairB -> pairA (relu, bf16 out)
    gemm_mfma_kernel<true, false, true, false><<<g, 256, 0, stream>>>(
        pBh, pBl, Whi, Wlo, enc_b1, nullptr, pAh, pAl, 256, 256);
    // enc2: pairA -> pairB (no relu, bf16 out)
    gemm_mfma_kernel<false, false, true, false><<<g, 256, 0, stream>>>(
        pAh, pAl, Whi + 65536, Wlo + 65536, enc_b2, nullptr, pBh, pBl, 256, 256);
    // gin: pairB -> xc (relu, f32 chunk-major out)
    gemm_mfma_kernel<true, true, false, true><<<g, 256, 0, stream>>>(
        pBh, pBl, Whi + 131072, Wlo + 131072, gin_b, xc, nullptr, nullptr, 256, 256);

    for (int i = 0; i < 3; ++i) {
        spmm_chunk_kernel<<<dim3(N / 16, 4), 256, 0, stream>>>(xc, ell, cntb, dinv, pAh, pAl);
        if (i < 2) {
            gemm_mfma_kernel<true, true, false, true><<<g, 256, 0, stream>>>(
                pAh, pAl, Whi + 196608 + 65536 * i, Wlo + 196608 + 65536 * i,
                gl_b + 256 * i, xc, nullptr, nullptr, 256, 256);
        } else {
            gemm_mfma_kernel<true, false, true, false><<<g, 256, 0, stream>>>(
                pAh, pAl, Whi + 196608 + 65536 * i, Wlo + 196608 + 65536 * i,
                gl_b + 256 * i, nullptr, pBh, pBl, 256, 256);
        }
    }
    // gout: pairB -> pairA (no relu, bf16 out)
    gemm_mfma_kernel<false, false, true, false><<<g, 256, 0, stream>>>(
        pBh, pBl, Whi + 393216, Wlo + 393216, gout_b, nullptr, pAh, pAl, 256, 256);
    // proj: pairA -> ne f32 row-major (relu), M=128
    gemm_mfma_kernel<true, true, false, false><<<dim3(N / 128, 1), 256, 0, stream>>>(
        pAh, pAl, Whi + 458752, Wlo + 458752, proj_b, ne, nullptr, nullptr, 256, 128);
    // hc1: fp32 legacy (K=128, M=64)
    gemm_kernel<true><<<dim3(N / 64, 1), 256, 0, stream>>>(ne, hc_w1, hc_b1, bufC, 128, 64);
    gemm_small_kernel<<<(N * 8 + 255) / 256, 256, 0, stream>>>(bufC, hc_w2, hc_b2, logits, N, 64, 8);
    col_mean_kernel<<<192, 128, 0, stream>>>(ne, gf, N, 128);
}

// Round 6
// 406.361 us; speedup vs baseline: 1.7110x; 1.0911x over previous
//
#include <hip/hip_runtime.h>

typedef unsigned long long u64;
typedef unsigned short ushort_t;
typedef unsigned int uint32;

#define NNODES 12288
#define WORDS 192   // 12288 / 64 bits per row
#define ELLW 256    // max neighbors per row (avg ~64, Poisson tail safe)
#define CHSZ (NNODES * 32)   // elements per 32-col chunk of x (8 chunks)

typedef __attribute__((ext_vector_type(8))) short short8_t;   // 8 bf16 (4 VGPRs)
typedef __attribute__((ext_vector_type(4))) float f32x4;      // MFMA C/D frag

// ---- bf16 split helpers (RNE) ----
__device__ __forceinline__ ushort_t f2bf(float f) {
    uint32 u = __float_as_uint(f);
    return (ushort_t)((u + 0x7fffu + ((u >> 16) & 1u)) >> 16);
}
__device__ __forceinline__ float bf2f(ushort_t h) {
    return __uint_as_float(((uint32)h) << 16);
}

// ---------------- adjacency build: bitmask M[s][d], MT[d][s] ----------------
__global__ void build_mask_kernel(const int* __restrict__ ei, u64* __restrict__ M,
                                  u64* __restrict__ MT, int E) {
    int e = blockIdx.x * blockDim.x + threadIdx.x;
    if (e >= E) return;
    int s = ei[e];
    int d = ei[E + e];
    atomicOr(&M[(size_t)s * WORDS + (d >> 6)], 1ull << (d & 63));
    atomicOr(&MT[(size_t)d * WORDS + (s >> 6)], 1ull << (s & 63));
}

// ---------------- bitmask -> u16 ELL neighbor list + cnt + dinv ----------------
__global__ __launch_bounds__(256) void ell_fill_kernel(
        const u64* __restrict__ M, const u64* __restrict__ MT,
        ushort_t* __restrict__ ell, int* __restrict__ cnt, float* __restrict__ dinv) {
    int row = blockIdx.x * 4 + (threadIdx.x >> 6);
    int lane = threadIdx.x & 63;
    const u64* rM  = M  + (size_t)row * WORDS;
    const u64* rMT = MT + (size_t)row * WORDS;
    u64 wm[3], wt[3];
    int pm = 0, pt = 0;
    #pragma unroll
    for (int k = 0; k < 3; ++k) {
        wm[k] = rM[lane + 64 * k];  pm += __popcll(wm[k]);
        wt[k] = rMT[lane + 64 * k]; pt += __popcll(wt[k]);
    }
    int inclM = pm, inclT = pt;
    #pragma unroll
    for (int off = 1; off < 64; off <<= 1) {
        int ym = __shfl_up(inclM, off, 64);
        int yt = __shfl_up(inclT, off, 64);
        if (lane >= off) { inclM += ym; inclT += yt; }
    }
    int exclM = inclM - pm;
    int exclT = inclT - pt;
    int totM = __shfl(inclM, 63, 64);
    int totT = __shfl(inclT, 63, 64);
    ushort_t* out = ell + (size_t)row * ELLW;
    int pos = exclM;
    #pragma unroll
    for (int k = 0; k < 3; ++k) {
        u64 bits = wm[k];
        int base = (lane + 64 * k) << 6;
        while (bits) { out[pos++] = (ushort_t)(base + __builtin_ctzll(bits)); bits &= bits - 1; }
    }
    pos = totM + exclT;
    #pragma unroll
    for (int k = 0; k < 3; ++k) {
        u64 bits = wt[k];
        int base = (lane + 64 * k) << 6;
        while (bits) { out[pos++] = (ushort_t)(base + __builtin_ctzll(bits)); bits &= bits - 1; }
    }
    if (lane == 0) {
        int n = totM + totT;
        cnt[row] = n;
        dinv[row] = 1.0f / ((float)n + 1e-8f);
    }
}

// ---------------- weight prep: split all GEMM weights into bf16 hi/lo -------
__global__ void wprep_kernel(const float* __restrict__ e1, const float* __restrict__ e2,
                             const float* __restrict__ gi, const float* __restrict__ gl,
                             const float* __restrict__ go, const float* __restrict__ pj,
                             ushort_t* __restrict__ hi, ushort_t* __restrict__ lo) {
    int i = blockIdx.x * 256 + threadIdx.x;
    if (i >= 491520) return;
    float v;
    if (i < 131072)      v = (i < 65536) ? e1[i] : e2[i - 65536];
    else if (i < 196608) v = gi[i - 131072];
    else if (i < 393216) v = gl[i - 196608];
    else if (i < 458752) v = go[i - 393216];
    else                 v = pj[i - 458752];
    ushort_t h = f2bf(v);
    hi[i] = h;
    lo[i] = f2bf(v - bf2f(h));
}

// ---------------- generic fp32 -> bf16 hi/lo split (vectorized) ----------------
__global__ void conv_split_kernel(const float* __restrict__ src, ushort_t* __restrict__ hi,
                                  ushort_t* __restrict__ lo, int n4) {
    int i = blockIdx.x * 256 + threadIdx.x;
    if (i >= n4) return;
    float4 v = ((const float4*)src)[i];
    ushort_t h0 = f2bf(v.x), h1 = f2bf(v.y), h2 = f2bf(v.z), h3 = f2bf(v.w);
    ushort4 hv = make_ushort4(h0, h1, h2, h3);
    ushort4 lv = make_ushort4(f2bf(v.x - bf2f(h0)), f2bf(v.y - bf2f(h1)),
                              f2bf(v.z - bf2f(h2)), f2bf(v.w - bf2f(h3)));
    ((ushort4*)hi)[i] = hv;
    ((ushort4*)lo)[i] = lv;
}

// ---------------- XCD-pinned chunked spmm ----------------
// x chunk-major xc[8][NNODES][32]. chunk = blockIdx.x & 7 ~= XCD id (dispatch
// round-robins workgroups over the 8 XCDs) -> each XCD's gathers stay within
// its own 1.57 MB L2-resident chunk. Wave = 8 rows x 8 lanes (float4 each:
// 128 B = one cache line per gather instruction), 4-deep ILP.
__global__ __launch_bounds__(256) void spmm_chunk_kernel(
        const float* __restrict__ xc, const ushort_t* __restrict__ ell,
        const int* __restrict__ cnt, const float* __restrict__ dinv,
        ushort_t* __restrict__ outh, ushort_t* __restrict__ outl) {
    int bx = blockIdx.x;
    int chunk = bx & 7;
    int rb = bx >> 3;                  // 0..383, 32 rows each
    int t = threadIdx.x;
    int lane = t & 63, w = t >> 6;
    int rloc = lane >> 3;              // sub-row 0..7
    int cl = lane & 7;                 // float4 column within 32-col chunk
    int row = rb * 32 + w * 8 + rloc;
    const float* xb = xc + (size_t)chunk * CHSZ + (cl << 2);
    int n = cnt[row];
    int nm = max(n, __shfl_xor(n, 8, 64));
    nm = max(nm, __shfl_xor(nm, 16, 64));
    nm = max(nm, __shfl_xor(nm, 32, 64));
    nm = (nm + 3) & ~3;
    const ushort_t* rell = ell + (size_t)row * ELLW;
    float ax = 0.f, ay = 0.f, az = 0.f, aw = 0.f;
    for (int i = 0; i < nm; i += 4) {
        ushort4 jj = *(const ushort4*)&rell[i];
        int j0 = jj.x, j1 = jj.y, j2 = jj.z, j3 = jj.w;
        float p0 = 1.f, p1 = 1.f, p2 = 1.f, p3 = 1.f;
        if (i + 0 >= n) { j0 = 0; p0 = 0.f; }
        if (i + 1 >= n) { j1 = 0; p1 = 0.f; }
        if (i + 2 >= n) { j2 = 0; p2 = 0.f; }
        if (i + 3 >= n) { j3 = 0; p3 = 0.f; }
        float4 v0 = *(const float4*)&xb[(size_t)j0 * 32];
        float4 v1 = *(const float4*)&xb[(size_t)j1 * 32];
        float4 v2 = *(const float4*)&xb[(size_t)j2 * 32];
        float4 v3 = *(const float4*)&xb[(size_t)j3 * 32];
        ax += v0.x * p0 + v1.x * p1 + v2.x * p2 + v3.x * p3;
        ay += v0.y * p0 + v1.y * p1 + v2.y * p2 + v3.y * p3;
        az += v0.z * p0 + v1.z * p1 + v2.z * p2 + v3.z * p3;
        aw += v0.w * p0 + v1.w * p1 + v2.w * p2 + v3.w * p3;
    }
    float4 xr = *(const float4*)&xb[(size_t)row * 32];
    float dv = dinv[row];
    float sx = xr.x + dv * ax;
    float sy = xr.y + dv * ay;
    float sz = xr.z + dv * az;
    float sw = xr.w + dv * aw;
    ushort_t hx = f2bf(sx), hy = f2bf(sy), hz = f2bf(sz), hw = f2bf(sw);
    size_t o = (size_t)row * 256 + (chunk << 5) + (cl << 2);
    *(ushort4*)&outh[o] = make_ushort4(hx, hy, hz, hw);
    *(ushort4*)&outl[o] = make_ushort4(f2bf(sx - bf2f(hx)), f2bf(sy - bf2f(hy)),
                                       f2bf(sz - bf2f(hz)), f2bf(sw - bf2f(hw)));
}

// ---------------- split-bf16 MFMA GEMM, 64x64 tiles ----------------
// Y = act(X @ W^T + b); 3-product split (lo*lo dropped). 768/384 blocks ->
// ~4 blocks/CU (32 KB dbuf LDS) for inter-block latency hiding. XCD banding:
// xcd = bx&7 owns row-tiles [xcd*RT/8, ...) so A stays in that XCD's L2.
__device__ __forceinline__ void stage64(const ushort_t* __restrict__ src, int rowbase,
                                        int K, int k0, ushort_t* half, int w, int lane) {
    int c16 = (w << 6) + lane;          // 256 16B-chunks cover 64x32 bf16 tile
    int r = c16 >> 2, q = c16 & 3;
    const ushort_t* gp = src + (size_t)(rowbase + r) * K + k0 + q * 8;
    __builtin_amdgcn_global_load_lds(
        (const __attribute__((address_space(1))) void*)gp,
        (__attribute__((address_space(3))) void*)(half + (w << 9)),
        16, 0, 0);
}

template<bool RELU, bool F32OUT, bool BF16OUT, bool CHUNKX>
__global__ __launch_bounds__(256) void gemm64_kernel(
        const ushort_t* __restrict__ Xhi, const ushort_t* __restrict__ Xlo,
        const ushort_t* __restrict__ Whi, const ushort_t* __restrict__ Wlo,
        const float* __restrict__ bias, float* __restrict__ Yf,
        ushort_t* __restrict__ Yhi, ushort_t* __restrict__ Ylo,
        int K, int Mcols, int CT) {
    __shared__ __align__(16) ushort_t lds[2][4][2048];   // [buf][Ahi,Alo,Bhi,Blo][64*32]
    int tid = threadIdx.x;
    int lane = tid & 63;
    int w = __builtin_amdgcn_readfirstlane(tid >> 6);
    int bx = blockIdx.x;
    int xcd = bx & 7;
    int k = bx >> 3;
    int RTper = (int)(gridDim.x >> 3) / CT;   // row-tiles per XCD band
    int rt = xcd * RTper + k / CT;
    int ct = k % CT;
    int row0 = rt * 64;
    int col0 = ct * 64;
    int wr = (w & 1) * 32;
    int wc = (w >> 1) * 32;
    int fr = lane & 15, fq = lane >> 4;

    f32x4 acc[2][2];
    #pragma unroll
    for (int a = 0; a < 2; ++a)
        #pragma unroll
        for (int b = 0; b < 2; ++b) {
            f32x4 z = {0.f, 0.f, 0.f, 0.f};
            acc[a][b] = z;
        }

    int NC = K >> 5;
    stage64(Xhi, row0, K, 0, &lds[0][0][0], w, lane);
    stage64(Xlo, row0, K, 0, &lds[0][1][0], w, lane);
    stage64(Whi, col0, K, 0, &lds[0][2][0], w, lane);
    stage64(Wlo, col0, K, 0, &lds[0][3][0], w, lane);
    __syncthreads();

    for (int c = 0; c < NC; ++c) {
        int bb = c & 1;
        if (c + 1 < NC) {
            int nb = (c + 1) & 1, k0 = (c + 1) << 5;
            stage64(Xhi, row0, K, k0, &lds[nb][0][0], w, lane);
            stage64(Xlo, row0, K, k0, &lds[nb][1][0], w, lane);
            stage64(Whi, col0, K, k0, &lds[nb][2][0], w, lane);
            stage64(Wlo, col0, K, k0, &lds[nb][3][0], w, lane);
        }
        const ushort_t* Ah = &lds[bb][0][0];
        const ushort_t* Al = &lds[bb][1][0];
        const ushort_t* Bh = &lds[bb][2][0];
        const ushort_t* Bl = &lds[bb][3][0];
        short8_t ah[2], al[2], bh[2], bl[2];
        #pragma unroll
        for (int t2 = 0; t2 < 2; ++t2) {
            int ao = (wr + 16 * t2 + fr) * 32 + fq * 8;
            int bo = (wc + 16 * t2 + fr) * 32 + fq * 8;
            ah[t2] = *(const short8_t*)&Ah[ao];
            al[t2] = *(const short8_t*)&Al[ao];
            bh[t2] = *(const short8_t*)&Bh[bo];
            bl[t2] = *(const short8_t*)&Bl[bo];
        }
        #pragma unroll
        for (int mt = 0; mt < 2; ++mt)
            #pragma unroll
            for (int nt = 0; nt < 2; ++nt) {
                f32x4 a = acc[mt][nt];
                a = __builtin_amdgcn_mfma_f32_16x16x32_bf16(ah[mt], bh[nt], a, 0, 0, 0);
                a = __builtin_amdgcn_mfma_f32_16x16x32_bf16(ah[mt], bl[nt], a, 0, 0, 0);
                a = __builtin_amdgcn_mfma_f32_16x16x32_bf16(al[mt], bh[nt], a, 0, 0, 0);
                acc[mt][nt] = a;
            }
        __syncthreads();
    }

    // epilogue (C/D: col = lane&15, row = (lane>>4)*4 + reg)
    float bcol[2];
    #pragma unroll
    for (int nt = 0; nt < 2; ++nt) bcol[nt] = bias[col0 + wc + 16 * nt + fr];
    #pragma unroll
    for (int mt = 0; mt < 2; ++mt) {
        int gr0 = row0 + wr + 16 * mt + fq * 4;
        #pragma unroll
        for (int nt = 0; nt < 2; ++nt) {
            int gc = col0 + wc + 16 * nt + fr;
            #pragma unroll
            for (int e = 0; e < 4; ++e) {
                float v = acc[mt][nt][e] + bcol[nt];
                if (RELU) v = fmaxf(v, 0.0f);
                size_t off;
                if (CHUNKX)
                    off = (size_t)(gc >> 5) * CHSZ + (size_t)(gr0 + e) * 32 + (gc & 31);
                else
                    off = (size_t)(gr0 + e) * Mcols + gc;
                if (F32OUT) Yf[off] = v;
                if (BF16OUT) {
                    ushort_t h = f2bf(v);
                    Yhi[off] = h;
                    Ylo[off] = f2bf(v - bf2f(h));
                }
            }
        }
    }
}

// ---------------- legacy fp32 64x64 GEMM (hc1 head: K=128, M=64) ----------------
template<bool RELU>
__global__ __launch_bounds__(256) void gemm_kernel(
        const float* __restrict__ X, const float* __restrict__ W,
        const float* __restrict__ bias, float* __restrict__ Y,
        int K, int Mcols) {
    const int BK = 32, LDP = 68;
    __shared__ float Xs[BK * LDP];
    __shared__ float Ws[BK * LDP];
    int tid = threadIdx.x;
    int row0 = blockIdx.x * 64;
    int col0 = blockIdx.y * 64;
    int tx = tid & 15, ty = tid >> 4;
    float acc[4][4] = {};
    for (int k0 = 0; k0 < K; k0 += BK) {
        #pragma unroll
        for (int i = 0; i < 2; ++i) {
            int f = tid + i * 256;
            int r = f >> 3;
            int kk = (f & 7) << 2;
            float4 vx = *(const float4*)&X[(size_t)(row0 + r) * K + k0 + kk];
            float4 vw = *(const float4*)&W[(size_t)(col0 + r) * K + k0 + kk];
            Xs[(kk + 0) * LDP + r] = vx.x;
            Xs[(kk + 1) * LDP + r] = vx.y;
            Xs[(kk + 2) * LDP + r] = vx.z;
            Xs[(kk + 3) * LDP + r] = vx.w;
            Ws[(kk + 0) * LDP + r] = vw.x;
            Ws[(kk + 1) * LDP + r] = vw.y;
            Ws[(kk + 2) * LDP + r] = vw.z;
            Ws[(kk + 3) * LDP + r] = vw.w;
        }
        __syncthreads();
        #pragma unroll
        for (int k = 0; k < BK; ++k) {
            float4 a = *(const float4*)&Xs[k * LDP + (ty << 2)];
            float4 b = *(const float4*)&Ws[k * LDP + (tx << 2)];
            float av[4] = {a.x, a.y, a.z, a.w};
            float bv[4] = {b.x, b.y, b.z, b.w};
            #pragma unroll
            for (int i2 = 0; i2 < 4; ++i2)
                #pragma unroll
                for (int j2 = 0; j2 < 4; ++j2)
                    acc[i2][j2] += av[i2] * bv[j2];
        }
        __syncthreads();
    }
    float4 b4 = *(const float4*)&bias[col0 + (tx << 2)];
    float bb[4] = {b4.x, b4.y, b4.z, b4.w};
    #pragma unroll
    for (int i2 = 0; i2 < 4; ++i2) {
        int row = row0 + (ty << 2) + i2;
        float4 v;
        float* vp = (float*)&v;
        #pragma unroll
        for (int j2 = 0; j2 < 4; ++j2) {
            float tv = acc[i2][j2] + bb[j2];
            if (RELU) tv = fmaxf(tv, 0.0f);
            vp[j2] = tv;
        }
        *(float4*)&Y[(size_t)row * Mcols + col0 + (tx << 2)] = v;
    }
}

// tiny head: Y[N,M] = X[N,K] @ W[M,K]^T + b, K<=64, M small (8)
__global__ void gemm_small_kernel(const float* __restrict__ X, const float* __restrict__ W,
                                  const float* __restrict__ bias, float* __restrict__ Y,
                                  int N, int K, int M) {
    int idx = blockIdx.x * blockDim.x + threadIdx.x;
    if (idx >= N * M) return;
    int r = idx / M, m = idx % M;
    float s = bias[m];
    const float* xr = X + (size_t)r * K;
    const float* wr = W + (size_t)m * K;
    for (int k = 0; k < K; ++k) s += xr[k] * wr[k];
    Y[idx] = s;
}

__global__ void col_mean_kernel(const float* __restrict__ ne, float* __restrict__ gf, int N, int D) {
    int t = threadIdx.x;   // 0..127
    float s = 0.0f;
    for (int r = blockIdx.x; r < N; r += gridDim.x) s += ne[(size_t)r * D + t];
    atomicAdd(&gf[t], s * (1.0f / (float)N));
}

extern "C" void kernel_launch(void* const* d_in, const int* in_sizes, int n_in,
                              void* d_out, int out_size, void* d_ws, size_t ws_size,
                              hipStream_t stream) {
    const int N = NNODES;
    const float* nf     = (const float*)d_in[0];
    const int*   ei     = (const int*)d_in[1];
    const float* enc_w1 = (const float*)d_in[2];
    const float* enc_b1 = (const float*)d_in[3];
    const float* enc_w2 = (const float*)d_in[4];
    const float* enc_b2 = (const float*)d_in[5];
    const float* gin_w  = (const float*)d_in[6];
    const float* gin_b  = (const float*)d_in[7];
    const float* gl_w   = (const float*)d_in[8];
    const float* gl_b   = (const float*)d_in[9];
    const float* gout_w = (const float*)d_in[10];
    const float* gout_b = (const float*)d_in[11];
    const float* proj_w = (const float*)d_in[12];
    const float* proj_b = (const float*)d_in[13];
    const float* hc_w1  = (const float*)d_in[14];
    const float* hc_b1  = (const float*)d_in[15];
    const float* hc_w2  = (const float*)d_in[16];
    const float* hc_b2  = (const float*)d_in[17];
    const int E = in_sizes[1] >> 1;

    // workspace carve (bytes):
    // [0, 37748736): masks M+MT -- dead after ell_fill; then aliased by
    //                xc (chunk-major f32, 12.6M) + pairA/pairB hi/lo (4x6.3M bf16)
    // [37748736, ...): ell u16 (6.3M), cnt, dinv, W arenas, bufC
    char* ws = (char*)d_ws;
    u64* M  = (u64*)ws;
    u64* MT = M + (size_t)N * WORDS;
    float*    xc  = (float*)ws;                                 // 12,582,912
    ushort_t* pAh = (ushort_t*)(ws + 12582912);                 //  6,291,456
    ushort_t* pAl = (ushort_t*)(ws + 18874368);
    ushort_t* pBh = (ushort_t*)(ws + 25165824);
    ushort_t* pBl = (ushort_t*)(ws + 31457280);                 // ends 37,748,736
    ushort_t* ell = (ushort_t*)(ws + 37748736);                 //  6,291,456
    int*      cntb = (int*)(ws + 44040192);
    float*    dinv = (float*)(ws + 44089344);
    ushort_t* Whi  = (ushort_t*)(ws + 44138496);                //    983,040
    ushort_t* Wlo  = (ushort_t*)(ws + 45121536);                //    983,040
    float*    bufC = (float*)(ws + 46104576);                   //  3,145,728

    float* ne     = (float*)d_out;                        // [N,128]
    float* logits = ne + (size_t)N * 128;                 // [N,8]
    float* gf     = logits + (size_t)N * 8;               // [128]

    hipMemsetAsync(M, 0, 2 * (size_t)N * WORDS * sizeof(u64), stream);
    hipMemsetAsync(gf, 0, 128 * sizeof(float), stream);

    build_mask_kernel<<<(E + 255) / 256, 256, 0, stream>>>(ei, M, MT, E);
    ell_fill_kernel<<<N / 4, 256, 0, stream>>>(M, MT, ell, cntb, dinv);
    // masks dead from here; xc/pairA/pairB may clobber them

    wprep_kernel<<<1920, 256, 0, stream>>>(enc_w1, enc_w2, gin_w, gl_w, gout_w, proj_w,
                                           Whi, Wlo);
    conv_split_kernel<<<3072, 256, 0, stream>>>(nf, pBh, pBl, N * 64);   // nf -> pairB

    const int G256 = (N / 64) * 4;   // 768 blocks for 256-col outputs
    const int G128 = (N / 64) * 2;   // 384 blocks for 128-col outputs
    // enc1: pairB -> pairA (relu, bf16 out)
    gemm64_kernel<true, false, true, false><<<G256, 256, 0, stream>>>(
        pBh, pBl, Whi, Wlo, enc_b1, nullptr, pAh, pAl, 256, 256, 4);
    // enc2: pairA -> pairB (no relu, bf16 out)
    gemm64_kernel<false, false, true, false><<<G256, 256, 0, stream>>>(
        pAh, pAl, Whi + 65536, Wlo + 65536, enc_b2, nullptr, pBh, pBl, 256, 256, 4);
    // gin: pairB -> xc (relu, f32 chunk-major out)
    gemm64_kernel<true, true, false, true><<<G256, 256, 0, stream>>>(
        pBh, pBl, Whi + 131072, Wlo + 131072, gin_b, xc, nullptr, nullptr, 256, 256, 4);

    for (int i = 0; i < 3; ++i) {
        spmm_chunk_kernel<<<(N / 32) * 8, 256, 0, stream>>>(xc, ell, cntb, dinv, pAh, pAl);
        if (i < 2) {
            gemm64_kernel<true, true, false, true><<<G256, 256, 0, stream>>>(
                pAh, pAl, Whi + 196608 + 65536 * i, Wlo + 196608 + 65536 * i,
                gl_b + 256 * i, xc, nullptr, nullptr, 256, 256, 4);
        } else {
            gemm64_kernel<true, false, true, false><<<G256, 256, 0, stream>>>(
                pAh, pAl, Whi + 196608 + 65536 * i, Wlo + 196608 + 65536 * i,
                gl_b + 256 * i, nullptr, pBh, pBl, 256, 256, 4);
        }
    }
    // gout: pairB -> pairA (no relu, bf16 out)
    gemm64_kernel<false, false, true, false><<<G256, 256, 0, stream>>>(
        pBh, pBl, Whi + 393216, Wlo + 393216, gout_b, nullptr, pAh, pAl, 256, 256, 4);
    // proj: pairA -> ne f32 row-major (relu), M=128
    gemm64_kernel<true, true, false, false><<<G128, 256, 0, stream>>>(
        pAh, pAl, Whi + 458752, Wlo + 458752, proj_b, ne, nullptr, nullptr, 256, 128, 2);
    // hc1: fp32 legacy (K=128, M=64)
    gemm_kernel<true><<<dim3(N / 64, 1), 256, 0, stream>>>(ne, hc_w1, hc_b1, bufC, 128, 64);
    gemm_small_kernel<<<(N * 8 + 255) / 256, 256, 0, stream>>>(bufC, hc_w2, hc_b2, logits, N, 64, 8);
    col_mean_kernel<<<192, 128, 0, stream>>>(ne, gf, N, 128);
}